// Round 1
// baseline (19227.209 us; speedup 1.0000x reference)
//
#include <hip/hip_runtime.h>
#include <hip/hip_bf16.h>
#include <math.h>

#define DEPTH_ 4
#define DIM_ 1024
#define HEADS_ 16
#define DHEAD_ 64
#define MLP_ 4096
#define CTX_ 1024
#define INNER_ 1024
#define B_ 4
#define N_ 1024
#define M_ 2048

// ---------------------------------------------------------------------------
// LayerNorm: one block per row (DIM_=1024 floats = 256 float4, 256 threads)
// ---------------------------------------------------------------------------
__global__ __launch_bounds__(256) void ln_kernel(
    const float* __restrict__ x, const float* __restrict__ g,
    const float* __restrict__ b, float* __restrict__ y) {
    int row = blockIdx.x;
    const float4* xr = (const float4*)(x + (size_t)row * DIM_);
    float4 v = xr[threadIdx.x];
    float s  = v.x + v.y + v.z + v.w;
    float ss = v.x * v.x + v.y * v.y + v.z * v.z + v.w * v.w;
    #pragma unroll
    for (int off = 32; off; off >>= 1) {
        s  += __shfl_down(s, off);
        ss += __shfl_down(ss, off);
    }
    __shared__ float red[10];
    int wid = threadIdx.x >> 6, lane = threadIdx.x & 63;
    if (lane == 0) { red[wid] = s; red[4 + wid] = ss; }
    __syncthreads();
    if (threadIdx.x == 0) {
        float ts  = red[0] + red[1] + red[2] + red[3];
        float tss = red[4] + red[5] + red[6] + red[7];
        float mu  = ts * (1.0f / DIM_);
        float var = tss * (1.0f / DIM_) - mu * mu;
        red[8] = mu;
        red[9] = rsqrtf(var + 1e-5f);
    }
    __syncthreads();
    float mu = red[8], rs = red[9];
    float4 gg = ((const float4*)g)[threadIdx.x];
    float4 bb = ((const float4*)b)[threadIdx.x];
    float4 o;
    o.x = (v.x - mu) * rs * gg.x + bb.x;
    o.y = (v.y - mu) * rs * gg.y + bb.y;
    o.z = (v.z - mu) * rs * gg.z + bb.z;
    o.w = (v.w - mu) * rs * gg.w + bb.w;
    ((float4*)(y + (size_t)row * DIM_))[threadIdx.x] = o;
}

// ---------------------------------------------------------------------------
// fp32 tiled GEMM: C[M,N] = A[M,K] @ B[K,N]  (+bias)(+gelu)(+residual-in-place)
// 128x128 tile, 256 threads, 8x8 per thread, BK=8.
// EPI: 0 = plain, 1 = +bias, 2 = +bias+residual (C += ...), 3 = +bias+gelu
// ---------------------------------------------------------------------------
template <int EPI>
__global__ __launch_bounds__(256) void gemm_kernel(
    const float* __restrict__ A, const float* __restrict__ Bm,
    const float* __restrict__ bias, float* __restrict__ C,
    int Mdim, int Ndim, int Kdim) {
    __shared__ float As[8][128];
    __shared__ float Bs[8][128];
    int t  = threadIdx.x;
    int tx = t & 15, ty = t >> 4;
    int m0 = blockIdx.y * 128, n0 = blockIdx.x * 128;

    float acc[8][8] = {};

    int arow = t >> 1, ac4 = (t & 1) * 4;    // A: 128 rows x 2 float4 (k)
    int brow = t >> 5, bc4 = (t & 31) * 4;   // B: 8 k-rows x 32 float4 (n)
    const float* Aptr = A + (size_t)(m0 + arow) * Kdim + ac4;
    const float* Bptr = Bm + (size_t)brow * Ndim + n0 + bc4;

    for (int k0 = 0; k0 < Kdim; k0 += 8) {
        float4 av = *(const float4*)(Aptr + k0);
        float4 bv = *(const float4*)(Bptr + (size_t)k0 * Ndim);
        __syncthreads();   // previous compute done before overwrite
        As[ac4 + 0][arow] = av.x;
        As[ac4 + 1][arow] = av.y;
        As[ac4 + 2][arow] = av.z;
        As[ac4 + 3][arow] = av.w;
        *(float4*)&Bs[brow][bc4] = bv;
        __syncthreads();
        #pragma unroll
        for (int kk = 0; kk < 8; ++kk) {
            float a[8], b[8];
            *(float4*)&a[0] = *(const float4*)&As[kk][ty * 8];
            *(float4*)&a[4] = *(const float4*)&As[kk][ty * 8 + 4];
            *(float4*)&b[0] = *(const float4*)&Bs[kk][tx * 8];
            *(float4*)&b[4] = *(const float4*)&Bs[kk][tx * 8 + 4];
            #pragma unroll
            for (int i = 0; i < 8; ++i)
                #pragma unroll
                for (int j = 0; j < 8; ++j) acc[i][j] += a[i] * b[j];
        }
    }

    #pragma unroll
    for (int i = 0; i < 8; ++i) {
        size_t base = (size_t)(m0 + ty * 8 + i) * Ndim + (n0 + tx * 8);
        float out[8];
        #pragma unroll
        for (int j = 0; j < 8; ++j) {
            float vv = acc[i][j];
            if constexpr (EPI >= 1) vv += bias[n0 + tx * 8 + j];
            if constexpr (EPI == 3)
                vv = 0.5f * vv * (1.0f + erff(vv * 0.70710678118654752f));
            if constexpr (EPI == 2) vv += C[base + j];
            out[j] = vv;
        }
        *(float4*)&C[base]     = *(float4*)&out[0];
        *(float4*)&C[base + 4] = *(float4*)&out[4];
    }
}

// ---------------------------------------------------------------------------
// Attention (flash-style, fp32): one q-row per thread, online softmax.
// IS_SA=1: Q/K/V packed in qkv buffer [B*N, 3*INNER]; key mask applied.
// IS_SA=0: Q in [B*N, INNER], K/V packed in kv buffer [B*M, 2*INNER].
//          (cross-attn query-mask is a per-row constant shift -> exact no-op)
// Grid: (N/256, HEADS, B). Block: 256 threads.
// ---------------------------------------------------------------------------
template <int KLEN, int IS_SA>
__global__ __launch_bounds__(256) void attn_kernel(
    const float* __restrict__ Qsrc, const float* __restrict__ KVsrc,
    const int* __restrict__ mask, float* __restrict__ O) {
    constexpr int TK = 32;
    __shared__ float Ks[TK][64];
    __shared__ float Vs[TK][64];
    __shared__ float negm[TK];

    int h = blockIdx.y, b = blockIdx.z;
    int n = blockIdx.x * 256 + threadIdx.x;

    const float* qptr;
    if constexpr (IS_SA)
        qptr = Qsrc + (size_t)(b * N_ + n) * (3 * INNER_) + h * DHEAD_;
    else
        qptr = Qsrc + (size_t)(b * N_ + n) * INNER_ + h * DHEAD_;

    float4 q4[16], o4[16];
    #pragma unroll
    for (int i = 0; i < 16; ++i) {
        q4[i] = ((const float4*)qptr)[i];
        o4[i] = make_float4(0.f, 0.f, 0.f, 0.f);
    }
    float mrun = -1e30f, lrun = 0.f;
    const float scale = 0.125f;  // 64^-0.5

    for (int kt = 0; kt < KLEN / TK; ++kt) {
        __syncthreads();
        #pragma unroll
        for (int rep = 0; rep < 2; ++rep) {
            int fi = threadIdx.x + rep * 256;  // 0..511 float4 slots
            int r = fi >> 4, c4 = (fi & 15) * 4;
            const float *kp, *vp;
            if constexpr (IS_SA) {
                size_t rb = (size_t)(b * N_ + kt * TK + r) * (3 * INNER_);
                kp = KVsrc + rb + INNER_ + h * DHEAD_ + c4;
                vp = KVsrc + rb + 2 * INNER_ + h * DHEAD_ + c4;
            } else {
                size_t rb = (size_t)(b * M_ + kt * TK + r) * (2 * INNER_);
                kp = KVsrc + rb + h * DHEAD_ + c4;
                vp = KVsrc + rb + INNER_ + h * DHEAD_ + c4;
            }
            *(float4*)&Ks[r][c4] = *(const float4*)kp;
            *(float4*)&Vs[r][c4] = *(const float4*)vp;
        }
        if (IS_SA && threadIdx.x < TK)
            negm[threadIdx.x] =
                1e11f * (float)(1 - mask[b * N_ + kt * TK + threadIdx.x]);
        __syncthreads();

        float s[TK];
        #pragma unroll
        for (int j = 0; j < TK; ++j) {
            float acc = 0.f;
            #pragma unroll
            for (int i = 0; i < 16; ++i) {
                float4 k4 = *(const float4*)&Ks[j][i * 4];
                acc += q4[i].x * k4.x + q4[i].y * k4.y + q4[i].z * k4.z +
                       q4[i].w * k4.w;
            }
            s[j] = acc * scale;
            if constexpr (IS_SA) s[j] -= negm[j];
        }
        float tmax = mrun;
        #pragma unroll
        for (int j = 0; j < TK; ++j) tmax = fmaxf(tmax, s[j]);
        float corr = __expf(mrun - tmax);
        lrun *= corr;
        #pragma unroll
        for (int i = 0; i < 16; ++i) {
            o4[i].x *= corr; o4[i].y *= corr; o4[i].z *= corr; o4[i].w *= corr;
        }
        mrun = tmax;
        #pragma unroll
        for (int j = 0; j < TK; ++j) {
            float p = __expf(s[j] - mrun);
            lrun += p;
            #pragma unroll
            for (int i = 0; i < 16; ++i) {
                float4 v4 = *(const float4*)&Vs[j][i * 4];
                o4[i].x += p * v4.x; o4[i].y += p * v4.y;
                o4[i].z += p * v4.z; o4[i].w += p * v4.w;
            }
        }
    }
    float inv = 1.f / lrun;
    float* optr = O + (size_t)(b * N_ + n) * INNER_ + h * DHEAD_;
    #pragma unroll
    for (int i = 0; i < 16; ++i) {
        float4 r;
        r.x = o4[i].x * inv; r.y = o4[i].y * inv;
        r.z = o4[i].z * inv; r.w = o4[i].w * inv;
        ((float4*)optr)[i] = r;
    }
}

// ---------------------------------------------------------------------------
extern "C" void kernel_launch(void* const* d_in, const int* in_sizes, int n_in,
                              void* d_out, int out_size, void* d_ws,
                              size_t ws_size, hipStream_t stream) {
    const float* x     = (const float*)d_in[0];
    const float* ctx   = (const float*)d_in[1];
    const int*   mask  = (const int*)d_in[2];
    const float* ln_g  = (const float*)d_in[3];
    const float* ln_b  = (const float*)d_in[4];
    const float* Wqkv  = (const float*)d_in[5];
    const float* Wo_sa = (const float*)d_in[6];
    const float* bo_sa = (const float*)d_in[7];
    const float* Wkv   = (const float*)d_in[8];
    const float* Wq    = (const float*)d_in[9];
    const float* Wo_ca = (const float*)d_in[10];
    const float* bo_ca = (const float*)d_in[11];
    const float* W1    = (const float*)d_in[12];
    const float* b1    = (const float*)d_in[13];
    const float* W2    = (const float*)d_in[14];
    const float* b2    = (const float*)d_in[15];
    float* xout = (float*)d_out;

    char* ws = (char*)d_ws;
    float* bufA = (float*)ws;                        // 16MB: ln out
    float* bufB = (float*)(ws + (16ull << 20));      // 64MB: qkv / kv / h1
    float* bufC = (float*)(ws + (80ull << 20));      // 16MB: attn out
    float* bufD = (float*)(ws + (96ull << 20));      // 16MB: q_ca

    hipMemcpyAsync(xout, x, sizeof(float) * B_ * N_ * DIM_,
                   hipMemcpyDeviceToDevice, stream);

    const int ROWS = B_ * N_;        // 4096
    const int CROWS = B_ * M_;       // 8192
    dim3 blk(256);

    for (int i = 0; i < DEPTH_; ++i) {
        const float* g  = ln_g + (size_t)(i * 3) * DIM_;
        const float* bb = ln_b + (size_t)(i * 3) * DIM_;
        // ---- self-attention ----
        ln_kernel<<<ROWS, blk, 0, stream>>>(xout, g, bb, bufA);
        gemm_kernel<0><<<dim3(3 * INNER_ / 128, ROWS / 128), blk, 0, stream>>>(
            bufA, Wqkv + (size_t)i * DIM_ * 3 * INNER_, nullptr, bufB,
            ROWS, 3 * INNER_, DIM_);
        attn_kernel<N_, 1><<<dim3(N_ / 256, HEADS_, B_), blk, 0, stream>>>(
            bufB, bufB, mask, bufC);
        gemm_kernel<2><<<dim3(DIM_ / 128, ROWS / 128), blk, 0, stream>>>(
            bufC, Wo_sa + (size_t)i * INNER_ * DIM_, bo_sa + (size_t)i * DIM_,
            xout, ROWS, DIM_, INNER_);
        // ---- cross-attention ----
        ln_kernel<<<ROWS, blk, 0, stream>>>(xout, g + DIM_, bb + DIM_, bufA);
        gemm_kernel<0><<<dim3(INNER_ / 128, ROWS / 128), blk, 0, stream>>>(
            bufA, Wq + (size_t)i * DIM_ * INNER_, nullptr, bufD,
            ROWS, INNER_, DIM_);
        gemm_kernel<0><<<dim3(2 * INNER_ / 128, CROWS / 128), blk, 0, stream>>>(
            ctx, Wkv + (size_t)i * CTX_ * 2 * INNER_, nullptr, bufB,
            CROWS, 2 * INNER_, CTX_);
        attn_kernel<M_, 0><<<dim3(N_ / 256, HEADS_, B_), blk, 0, stream>>>(
            bufD, bufB, mask, bufC);
        gemm_kernel<2><<<dim3(DIM_ / 128, ROWS / 128), blk, 0, stream>>>(
            bufC, Wo_ca + (size_t)i * INNER_ * DIM_, bo_ca + (size_t)i * DIM_,
            xout, ROWS, DIM_, INNER_);
        // ---- feed-forward ----
        ln_kernel<<<ROWS, blk, 0, stream>>>(xout, g + 2 * DIM_, bb + 2 * DIM_,
                                            bufA);
        gemm_kernel<3><<<dim3(MLP_ / 128, ROWS / 128), blk, 0, stream>>>(
            bufA, W1 + (size_t)i * DIM_ * MLP_, b1 + (size_t)i * MLP_, bufB,
            ROWS, MLP_, DIM_);
        gemm_kernel<2><<<dim3(DIM_ / 128, ROWS / 128), blk, 0, stream>>>(
            bufB, W2 + (size_t)i * MLP_ * DIM_, b2 + (size_t)i * DIM_, xout,
            ROWS, DIM_, MLP_);
    }
}

// Round 2
// 2674.454 us; speedup vs baseline: 7.1892x; 7.1892x over previous
//
#include <hip/hip_runtime.h>
#include <math.h>

#define DEPTH_ 4
#define DIM_ 1024
#define HEADS_ 16
#define DHEAD_ 64
#define MLP_ 4096
#define CTX_ 1024
#define INNER_ 1024
#define B_ 4
#define N_ 1024
#define M_ 2048

typedef unsigned short u16;
typedef __attribute__((ext_vector_type(4))) unsigned short u16x4;
typedef __attribute__((ext_vector_type(8))) short bf16x8;
typedef __attribute__((ext_vector_type(4))) float f32x4;

__device__ __forceinline__ u16 f2bf(float f) {
    unsigned u = __float_as_uint(f);
    return (u16)((u + 0x7fffu + ((u >> 16) & 1u)) >> 16);
}

#define GLOAD16(gp, sp)                                                        \
    __builtin_amdgcn_global_load_lds(                                          \
        (const __attribute__((address_space(1))) void*)(gp),                   \
        (__attribute__((address_space(3))) void*)(sp), 16, 0, 0)

// ---------------------------------------------------------------------------
// LayerNorm fp32 -> bf16 out. One block per row, 256 threads x float4.
// ---------------------------------------------------------------------------
__global__ __launch_bounds__(256) void ln_kernel(
    const float* __restrict__ x, const float* __restrict__ g,
    const float* __restrict__ b, u16* __restrict__ y) {
    int row = blockIdx.x;
    float4 v = ((const float4*)(x + (size_t)row * DIM_))[threadIdx.x];
    float s  = v.x + v.y + v.z + v.w;
    float ss = v.x * v.x + v.y * v.y + v.z * v.z + v.w * v.w;
    #pragma unroll
    for (int off = 32; off; off >>= 1) {
        s  += __shfl_down(s, off);
        ss += __shfl_down(ss, off);
    }
    __shared__ float red[10];
    int wid = threadIdx.x >> 6, lane = threadIdx.x & 63;
    if (lane == 0) { red[wid] = s; red[4 + wid] = ss; }
    __syncthreads();
    if (threadIdx.x == 0) {
        float ts  = red[0] + red[1] + red[2] + red[3];
        float tss = red[4] + red[5] + red[6] + red[7];
        float mu  = ts * (1.0f / DIM_);
        float var = tss * (1.0f / DIM_) - mu * mu;
        red[8] = mu;
        red[9] = rsqrtf(var + 1e-5f);
    }
    __syncthreads();
    float mu = red[8], rs = red[9];
    float4 gg = ((const float4*)g)[threadIdx.x];
    float4 bb = ((const float4*)b)[threadIdx.x];
    u16x4 o;
    o[0] = f2bf((v.x - mu) * rs * gg.x + bb.x);
    o[1] = f2bf((v.y - mu) * rs * gg.y + bb.y);
    o[2] = f2bf((v.z - mu) * rs * gg.z + bb.z);
    o[3] = f2bf((v.w - mu) * rs * gg.w + bb.w);
    ((u16x4*)(y + (size_t)row * DIM_))[threadIdx.x] = o;
}

// ---------------------------------------------------------------------------
// fp32 -> bf16 cast (context), float4 per thread
// ---------------------------------------------------------------------------
__global__ __launch_bounds__(256) void cast_kernel(const float* __restrict__ in,
                                                   u16* __restrict__ out) {
    int i = blockIdx.x * 256 + threadIdx.x;
    float4 v = ((const float4*)in)[i];
    u16x4 o = {f2bf(v.x), f2bf(v.y), f2bf(v.z), f2bf(v.w)};
    ((u16x4*)out)[i] = o;
}

// ---------------------------------------------------------------------------
// Weight transpose + cast: W[K][N] fp32 -> Wt[N][K] bf16. 32x32 tiles.
// ---------------------------------------------------------------------------
__global__ __launch_bounds__(256) void transpose_cast(
    const float* __restrict__ W, u16* __restrict__ Wt, int Kdim, int Ndim) {
    __shared__ float tile[32][33];
    int bx = blockIdx.x * 32;  // n
    int by = blockIdx.y * 32;  // k
    int t = threadIdx.x;
    int kl = t >> 3, n4 = (t & 7) * 4;
    float4 v = *(const float4*)(W + (size_t)(by + kl) * Ndim + bx + n4);
    tile[kl][n4 + 0] = v.x; tile[kl][n4 + 1] = v.y;
    tile[kl][n4 + 2] = v.z; tile[kl][n4 + 3] = v.w;
    __syncthreads();
    int nl = t >> 3, k4 = (t & 7) * 4;
    u16x4 o;
    #pragma unroll
    for (int j = 0; j < 4; ++j) o[j] = f2bf(tile[k4 + j][nl]);
    *(u16x4*)(Wt + (size_t)(bx + nl) * Kdim + by + k4) = o;
}

// ---------------------------------------------------------------------------
// MFMA GEMM (m97 structure): C[M,N] = A[M,K] * Bt[N,K]^T, bf16 in, fp32 acc.
// 128x128 tile, BK=32, 4 waves (2x2), 16 mfma/K-step, global_load_lds staging.
// EPI: 0 = bf16 out; 1 = +bias +gelu, bf16 out; 2 = fp32 residual += acc+bias
// ---------------------------------------------------------------------------
template <int EPI>
__global__ __launch_bounds__(256) void gemm_mfma(
    const u16* __restrict__ A, const u16* __restrict__ Bt,
    const float* __restrict__ bias, void* __restrict__ Cout,
    int Mdim, int Ndim, int Kdim) {
    __shared__ __align__(16) u16 As[128 * 32];
    __shared__ __align__(16) u16 Bs[128 * 32];
    const int t = threadIdx.x;
    const int lane = t & 63, w = t >> 6;
    const int c = lane & 15, g = lane >> 4;
    const int wy = w >> 1, wx = w & 1;
    const int m0 = blockIdx.y * 128, n0 = blockIdx.x * 128;

    f32x4 acc[4][4] = {};

    // staging: wave w owns chunks 2w, 2w+1 (16 rows each) of A-tile and B-tile
    const int srow = w * 32 + (lane >> 2);
    const int scb  = (lane & 3) * 8;
    const u16* Ag = A + (size_t)(m0 + srow) * Kdim + scb;
    const u16* Bg = Bt + (size_t)(n0 + srow) * Kdim + scb;
    u16* AsW = As + w * 1024;
    u16* BsW = Bs + w * 1024;

    for (int k0 = 0; k0 < Kdim; k0 += 32) {
        __syncthreads();
        GLOAD16(Ag + k0, AsW);
        GLOAD16(Ag + k0 + (size_t)16 * Kdim, AsW + 512);
        GLOAD16(Bg + k0, BsW);
        GLOAD16(Bg + k0 + (size_t)16 * Kdim, BsW + 512);
        __syncthreads();
        bf16x8 a[4], b[4];
        #pragma unroll
        for (int i = 0; i < 4; ++i)
            a[i] = *(const bf16x8*)(As + (wy * 64 + i * 16 + c) * 32 + g * 8);
        #pragma unroll
        for (int i = 0; i < 4; ++i)
            b[i] = *(const bf16x8*)(Bs + (wx * 64 + i * 16 + c) * 32 + g * 8);
        #pragma unroll
        for (int i = 0; i < 4; ++i)
            #pragma unroll
            for (int j = 0; j < 4; ++j)
                acc[i][j] = __builtin_amdgcn_mfma_f32_16x16x32_bf16(
                    a[i], b[j], acc[i][j], 0, 0, 0);
    }

    #pragma unroll
    for (int i = 0; i < 4; ++i) {
        int row = m0 + wy * 64 + i * 16 + g * 4;
        #pragma unroll
        for (int j = 0; j < 4; ++j) {
            int col = n0 + wx * 64 + j * 16 + c;
            #pragma unroll
            for (int r = 0; r < 4; ++r) {
                float v = acc[i][j][r];
                size_t idx = (size_t)(row + r) * Ndim + col;
                if constexpr (EPI == 0) {
                    ((u16*)Cout)[idx] = f2bf(v);
                } else if constexpr (EPI == 1) {
                    v += bias[col];
                    v = 0.5f * v * (1.0f + erff(v * 0.70710678118654752f));
                    ((u16*)Cout)[idx] = f2bf(v);
                } else {
                    float* Cf = (float*)Cout;
                    Cf[idx] += v + bias[col];
                }
            }
        }
    }
}

// ---------------------------------------------------------------------------
// MFMA flash attention. Block = 4 waves, 64 q-rows per block (16/wave), one
// (b,h). K-tile = 32 keys staged in LDS (K row-major XOR-swizzled; V
// transposed + swizzled). Softmax per 16-lane group via shfl_xor. P re-shaped
// to A-fragment through per-wave swizzled LDS buffer.
// ---------------------------------------------------------------------------
template <int KLEN, int IS_SA>
__global__ __launch_bounds__(256) void attn_mfma(
    const u16* __restrict__ Qsrc, const u16* __restrict__ KVsrc,
    const int* __restrict__ mask, u16* __restrict__ O) {
    constexpr int QSTR  = IS_SA ? 3 * INNER_ : INNER_;
    constexpr int KVSTR = IS_SA ? 3 * INNER_ : 2 * INNER_;
    constexpr int KOFF  = IS_SA ? INNER_ : 0;
    constexpr int VOFF  = IS_SA ? 2 * INNER_ : INNER_;

    __shared__ __align__(16) u16 Ks[32 * 64];
    __shared__ __align__(16) u16 Vt[64 * 32];
    __shared__ __align__(16) u16 Pl[4 * 512];
    __shared__ float negm[32];

    const int t = threadIdx.x;
    const int lane = t & 63, w = t >> 6;
    const int c = lane & 15, g = lane >> 4;
    const int h = blockIdx.y, bb = blockIdx.z;
    const int q0 = blockIdx.x * 64 + w * 16;
    const int kvbase = bb * (IS_SA ? N_ : M_);

    // Q fragments (16 q-rows x 64 d), held in registers
    const u16* qp = Qsrc + (size_t)(bb * N_ + q0 + c) * QSTR + h * 64 + g * 8;
    bf16x8 qf[2];
    qf[0] = *(const bf16x8*)qp;
    qf[1] = *(const bf16x8*)(qp + 32);

    f32x4 o[4] = {};
    float mr[4] = {-1e30f, -1e30f, -1e30f, -1e30f};
    float lr[4] = {0.f, 0.f, 0.f, 0.f};
    u16* Pw = Pl + w * 512;

    for (int kt = 0; kt < KLEN / 32; ++kt) {
        __syncthreads();
        {   // stage K tile [32 kv][64 d], XOR-swizzled 16B blocks
            int r = t >> 3, cb = t & 7;
            const u16* kp = KVsrc + (size_t)(kvbase + kt * 32 + r) * KVSTR +
                            KOFF + h * 64 + cb * 8;
            bf16x8 kv = *(const bf16x8*)kp;
            *(bf16x8*)(Ks + r * 64 + ((cb ^ (r & 7)) * 8)) = kv;
            // stage V transposed: Vt[64 d][32 kv], swizzled
            const u16* vp = KVsrc + (size_t)(kvbase + kt * 32 + r) * KVSTR +
                            VOFF + h * 64 + cb * 8;
            bf16x8 vv = *(const bf16x8*)vp;
            #pragma unroll
            for (int j = 0; j < 8; ++j) {
                int d = cb * 8 + j;
                int blk = (r >> 3) ^ ((d >> 3) & 3);
                Vt[d * 32 + blk * 8 + (r & 7)] = (u16)vv[j];
            }
            if (IS_SA && t < 32)
                negm[t] = 1e11f * (float)(1 - mask[bb * N_ + kt * 32 + t]);
        }
        __syncthreads();

        // S = Q K^T * scale (- mask): two 16-key blocks
        f32x4 sv[2];
        #pragma unroll
        for (int kb = 0; kb < 2; ++kb) {
            f32x4 s = {0.f, 0.f, 0.f, 0.f};
            int krow = kb * 16 + c;
            #pragma unroll
            for (int f = 0; f < 2; ++f) {
                bf16x8 kf = *(const bf16x8*)(
                    Ks + krow * 64 + (((g + 4 * f) ^ (krow & 7)) * 8));
                s = __builtin_amdgcn_mfma_f32_16x16x32_bf16(qf[f], kf, s, 0, 0, 0);
            }
            float nm = IS_SA ? negm[krow] : 0.f;
            #pragma unroll
            for (int r = 0; r < 4; ++r) s[r] = s[r] * 0.125f - nm;
            sv[kb] = s;
        }
        // row max over 32 keys (lanes c share a q-row per reg within group g)
        float tm[4], mn[4], corr[4];
        #pragma unroll
        for (int r = 0; r < 4; ++r) {
            float v = fmaxf(sv[0][r], sv[1][r]);
            v = fmaxf(v, __shfl_xor(v, 1));
            v = fmaxf(v, __shfl_xor(v, 2));
            v = fmaxf(v, __shfl_xor(v, 4));
            v = fmaxf(v, __shfl_xor(v, 8));
            tm[r] = v;
            mn[r] = fmaxf(mr[r], v);
            corr[r] = __expf(mr[r] - mn[r]);
            mr[r] = mn[r];
        }
        // P = exp(S - m), row sums, rescale O and l
        float rs[4];
        #pragma unroll
        for (int r = 0; r < 4; ++r) {
            sv[0][r] = __expf(sv[0][r] - mn[r]);
            sv[1][r] = __expf(sv[1][r] - mn[r]);
            float v = sv[0][r] + sv[1][r];
            v += __shfl_xor(v, 1);
            v += __shfl_xor(v, 2);
            v += __shfl_xor(v, 4);
            v += __shfl_xor(v, 8);
            rs[r] = v;
            lr[r] = lr[r] * corr[r] + v;
        }
        #pragma unroll
        for (int db = 0; db < 4; ++db)
            #pragma unroll
            for (int r = 0; r < 4; ++r) o[db][r] *= corr[r];

        // P -> bf16 -> per-wave LDS (swizzled), reshape to A-fragment
        #pragma unroll
        for (int kb = 0; kb < 2; ++kb)
            #pragma unroll
            for (int r = 0; r < 4; ++r) {
                int ql = g * 4 + r;
                int k = kb * 16 + c;
                Pw[ql * 32 + (((k >> 3) ^ g) * 8) + (k & 7)] = f2bf(sv[kb][r]);
            }
        bf16x8 pa = *(const bf16x8*)(Pw + c * 32 + ((g ^ (c >> 2)) * 8));

        // O += P * V
        #pragma unroll
        for (int db = 0; db < 4; ++db) {
            int d = db * 16 + c;
            bf16x8 vf = *(const bf16x8*)(
                Vt + d * 32 + ((g ^ ((d >> 3) & 3)) * 8));
            o[db] = __builtin_amdgcn_mfma_f32_16x16x32_bf16(pa, vf, o[db], 0, 0, 0);
        }
    }

    float inv[4];
    #pragma unroll
    for (int r = 0; r < 4; ++r) inv[r] = 1.f / lr[r];
    #pragma unroll
    for (int db = 0; db < 4; ++db)
        #pragma unroll
        for (int r = 0; r < 4; ++r) {
            int qrow = q0 + g * 4 + r;
            O[(size_t)(bb * N_ + qrow) * INNER_ + h * 64 + db * 16 + c] =
                f2bf(o[db][r] * inv[r]);
        }
}

// ---------------------------------------------------------------------------
extern "C" void kernel_launch(void* const* d_in, const int* in_sizes, int n_in,
                              void* d_out, int out_size, void* d_ws,
                              size_t ws_size, hipStream_t stream) {
    const float* x     = (const float*)d_in[0];
    const float* ctx   = (const float*)d_in[1];
    const int*   mask  = (const int*)d_in[2];
    const float* ln_g  = (const float*)d_in[3];
    const float* ln_b  = (const float*)d_in[4];
    const float* Wqkv  = (const float*)d_in[5];
    const float* Wo_sa = (const float*)d_in[6];
    const float* bo_sa = (const float*)d_in[7];
    const float* Wkv   = (const float*)d_in[8];
    const float* Wq    = (const float*)d_in[9];
    const float* Wo_ca = (const float*)d_in[10];
    const float* bo_ca = (const float*)d_in[11];
    const float* W1    = (const float*)d_in[12];
    const float* b1    = (const float*)d_in[13];
    const float* W2    = (const float*)d_in[14];
    const float* b2    = (const float*)d_in[15];
    float* xout = (float*)d_out;

    char* ws = (char*)d_ws;
    u16* lnout = (u16*)ws;                        // 8MB
    u16* big   = (u16*)(ws + (8ull << 20));       // 32MB: qkv / kv / h1
    u16* aout  = (u16*)(ws + (40ull << 20));      // 8MB: attn out
    u16* qca   = (u16*)(ws + (48ull << 20));      // 8MB
    u16* ctxb  = (u16*)(ws + (56ull << 20));      // 16MB
    u16* wt    = (u16*)(ws + (72ull << 20));      // 8MB: transposed weight

    hipMemcpyAsync(xout, x, sizeof(float) * B_ * N_ * DIM_,
                   hipMemcpyDeviceToDevice, stream);
    cast_kernel<<<B_ * M_ * CTX_ / 1024, 256, 0, stream>>>(ctx, ctxb);

    const int ROWS = B_ * N_;    // 4096
    const int CROWS = B_ * M_;   // 8192
    dim3 blk(256);

    for (int i = 0; i < DEPTH_; ++i) {
        const float* g  = ln_g + (size_t)(i * 3) * DIM_;
        const float* bb = ln_b + (size_t)(i * 3) * DIM_;

        // ---- self-attention ----
        ln_kernel<<<ROWS, blk, 0, stream>>>(xout, g, bb, lnout);
        transpose_cast<<<dim3(3 * INNER_ / 32, DIM_ / 32), blk, 0, stream>>>(
            Wqkv + (size_t)i * DIM_ * 3 * INNER_, wt, DIM_, 3 * INNER_);
        gemm_mfma<0><<<dim3(3 * INNER_ / 128, ROWS / 128), blk, 0, stream>>>(
            lnout, wt, nullptr, big, ROWS, 3 * INNER_, DIM_);
        attn_mfma<N_, 1><<<dim3(N_ / 64, HEADS_, B_), blk, 0, stream>>>(
            big, big, mask, aout);
        transpose_cast<<<dim3(DIM_ / 32, INNER_ / 32), blk, 0, stream>>>(
            Wo_sa + (size_t)i * INNER_ * DIM_, wt, INNER_, DIM_);
        gemm_mfma<2><<<dim3(DIM_ / 128, ROWS / 128), blk, 0, stream>>>(
            aout, wt, bo_sa + (size_t)i * DIM_, xout, ROWS, DIM_, INNER_);

        // ---- cross-attention ----
        ln_kernel<<<ROWS, blk, 0, stream>>>(xout, g + DIM_, bb + DIM_, lnout);
        transpose_cast<<<dim3(INNER_ / 32, DIM_ / 32), blk, 0, stream>>>(
            Wq + (size_t)i * DIM_ * INNER_, wt, DIM_, INNER_);
        gemm_mfma<0><<<dim3(INNER_ / 128, ROWS / 128), blk, 0, stream>>>(
            lnout, wt, nullptr, qca, ROWS, INNER_, DIM_);
        transpose_cast<<<dim3(2 * INNER_ / 32, CTX_ / 32), blk, 0, stream>>>(
            Wkv + (size_t)i * CTX_ * 2 * INNER_, wt, CTX_, 2 * INNER_);
        gemm_mfma<0><<<dim3(2 * INNER_ / 128, CROWS / 128), blk, 0, stream>>>(
            ctxb, wt, nullptr, big, CROWS, 2 * INNER_, CTX_);
        attn_mfma<M_, 0><<<dim3(N_ / 64, HEADS_, B_), blk, 0, stream>>>(
            qca, big, mask, aout);
        transpose_cast<<<dim3(DIM_ / 32, INNER_ / 32), blk, 0, stream>>>(
            Wo_ca + (size_t)i * INNER_ * DIM_, wt, INNER_, DIM_);
        gemm_mfma<2><<<dim3(DIM_ / 128, ROWS / 128), blk, 0, stream>>>(
            aout, wt, bo_ca + (size_t)i * DIM_, xout, ROWS, DIM_, INNER_);

        // ---- feed-forward ----
        ln_kernel<<<ROWS, blk, 0, stream>>>(xout, g + 2 * DIM_, bb + 2 * DIM_,
                                            lnout);
        transpose_cast<<<dim3(MLP_ / 32, DIM_ / 32), blk, 0, stream>>>(
            W1 + (size_t)i * DIM_ * MLP_, wt, DIM_, MLP_);
        gemm_mfma<1><<<dim3(MLP_ / 128, ROWS / 128), blk, 0, stream>>>(
            lnout, wt, b1 + (size_t)i * MLP_, big, ROWS, MLP_, DIM_);
        transpose_cast<<<dim3(DIM_ / 32, MLP_ / 32), blk, 0, stream>>>(
            W2 + (size_t)i * MLP_ * DIM_, wt, MLP_, DIM_);
        gemm_mfma<2><<<dim3(DIM_ / 128, ROWS / 128), blk, 0, stream>>>(
            big, wt, b2 + (size_t)i * DIM_, xout, ROWS, DIM_, MLP_);
    }
}

// Round 3
// 2213.632 us; speedup vs baseline: 8.6858x; 1.2082x over previous
//
#include <hip/hip_runtime.h>
#include <math.h>

#define DEPTH_ 4
#define DIM_ 1024
#define HEADS_ 16
#define DHEAD_ 64
#define MLP_ 4096
#define CTX_ 1024
#define INNER_ 1024
#define B_ 4
#define N_ 1024
#define M_ 2048

typedef unsigned short u16;
typedef __attribute__((ext_vector_type(4))) unsigned short u16x4;
typedef __attribute__((ext_vector_type(8))) short bf16x8;
typedef __attribute__((ext_vector_type(4))) float f32x4;
typedef __attribute__((ext_vector_type(4))) int i32x4;

__device__ __forceinline__ u16 f2bf(float f) {
    unsigned u = __float_as_uint(f);
    return (u16)((u + 0x7fffu + ((u >> 16) & 1u)) >> 16);
}

#define GLOAD16(gp, sp)                                                        \
    __builtin_amdgcn_global_load_lds(                                          \
        (const __attribute__((address_space(1))) void*)(gp),                   \
        (__attribute__((address_space(3))) void*)(sp), 16, 0, 0)

// ---------------------------------------------------------------------------
// LayerNorm fp32 -> bf16 out. One block per row, 256 threads x float4.
// ---------------------------------------------------------------------------
__global__ __launch_bounds__(256) void ln_kernel(
    const float* __restrict__ x, const float* __restrict__ g,
    const float* __restrict__ b, u16* __restrict__ y) {
    int row = blockIdx.x;
    float4 v = ((const float4*)(x + (size_t)row * DIM_))[threadIdx.x];
    float s  = v.x + v.y + v.z + v.w;
    float ss = v.x * v.x + v.y * v.y + v.z * v.z + v.w * v.w;
    #pragma unroll
    for (int off = 32; off; off >>= 1) {
        s  += __shfl_down(s, off);
        ss += __shfl_down(ss, off);
    }
    __shared__ float red[10];
    int wid = threadIdx.x >> 6, lane = threadIdx.x & 63;
    if (lane == 0) { red[wid] = s; red[4 + wid] = ss; }
    __syncthreads();
    if (threadIdx.x == 0) {
        float ts  = red[0] + red[1] + red[2] + red[3];
        float tss = red[4] + red[5] + red[6] + red[7];
        float mu  = ts * (1.0f / DIM_);
        float var = tss * (1.0f / DIM_) - mu * mu;
        red[8] = mu;
        red[9] = rsqrtf(var + 1e-5f);
    }
    __syncthreads();
    float mu = red[8], rs = red[9];
    float4 gg = ((const float4*)g)[threadIdx.x];
    float4 bb = ((const float4*)b)[threadIdx.x];
    u16x4 o;
    o[0] = f2bf((v.x - mu) * rs * gg.x + bb.x);
    o[1] = f2bf((v.y - mu) * rs * gg.y + bb.y);
    o[2] = f2bf((v.z - mu) * rs * gg.z + bb.z);
    o[3] = f2bf((v.w - mu) * rs * gg.w + bb.w);
    ((u16x4*)(y + (size_t)row * DIM_))[threadIdx.x] = o;
}

// ---------------------------------------------------------------------------
// fp32 -> bf16 cast (context), float4 per thread
// ---------------------------------------------------------------------------
__global__ __launch_bounds__(256) void cast_kernel(const float* __restrict__ in,
                                                   u16* __restrict__ out) {
    int i = blockIdx.x * 256 + threadIdx.x;
    float4 v = ((const float4*)in)[i];
    u16x4 o = {f2bf(v.x), f2bf(v.y), f2bf(v.z), f2bf(v.w)};
    ((u16x4*)out)[i] = o;
}

// ---------------------------------------------------------------------------
// Weight transpose + cast: W[K][N] fp32 -> Wt[N][K] bf16. 32x32 tiles.
// ---------------------------------------------------------------------------
__global__ __launch_bounds__(256) void transpose_cast(
    const float* __restrict__ W, u16* __restrict__ Wt, int Kdim, int Ndim) {
    __shared__ float tile[32][33];
    int bx = blockIdx.x * 32;  // n
    int by = blockIdx.y * 32;  // k
    int t = threadIdx.x;
    int kl = t >> 3, n4 = (t & 7) * 4;
    float4 v = *(const float4*)(W + (size_t)(by + kl) * Ndim + bx + n4);
    tile[kl][n4 + 0] = v.x; tile[kl][n4 + 1] = v.y;
    tile[kl][n4 + 2] = v.z; tile[kl][n4 + 3] = v.w;
    __syncthreads();
    int nl = t >> 3, k4 = (t & 7) * 4;
    u16x4 o;
    #pragma unroll
    for (int j = 0; j < 4; ++j) o[j] = f2bf(tile[k4 + j][nl]);
    *(u16x4*)(Wt + (size_t)(bx + nl) * Kdim + by + k4) = o;
}

// ---------------------------------------------------------------------------
// MFMA GEMM (m97 structure): C[M,N] = A[M,K] * Bt[N,K]^T, bf16 in, fp32 acc.
// 128x128 tile, BK=32, 4 waves (2x2), 16 mfma/K-step, global_load_lds staging.
// EPI: 0 = bf16 out; 1 = +bias+gelu bf16; 2 = fp32 residual += acc+bias;
//      4 = bf16 out + V-part (col>=2048) transposed to vt (QKV gemm, rpb=1024)
//      5 = bf16 out + V-part (col>=1024) transposed to vt (KV  gemm, rpb=2048)
// ---------------------------------------------------------------------------
template <int EPI>
__global__ __launch_bounds__(256) void gemm_mfma(
    const u16* __restrict__ A, const u16* __restrict__ Bt,
    const float* __restrict__ bias, void* __restrict__ Cout,
    u16* __restrict__ vt, int Mdim, int Ndim, int Kdim) {
    __shared__ __align__(16) u16 As[128 * 32];
    __shared__ __align__(16) u16 Bs[128 * 32];
    const int t = threadIdx.x;
    const int lane = t & 63, w = t >> 6;
    const int c = lane & 15, g = lane >> 4;
    const int wy = w >> 1, wx = w & 1;
    const int m0 = blockIdx.y * 128, n0 = blockIdx.x * 128;

    f32x4 acc[4][4] = {};

    const int srow = w * 32 + (lane >> 2);
    const int scb  = (lane & 3) * 8;
    const u16* Ag = A + (size_t)(m0 + srow) * Kdim + scb;
    const u16* Bg = Bt + (size_t)(n0 + srow) * Kdim + scb;
    u16* AsW = As + w * 1024;
    u16* BsW = Bs + w * 1024;

    for (int k0 = 0; k0 < Kdim; k0 += 32) {
        __syncthreads();
        GLOAD16(Ag + k0, AsW);
        GLOAD16(Ag + k0 + (size_t)16 * Kdim, AsW + 512);
        GLOAD16(Bg + k0, BsW);
        GLOAD16(Bg + k0 + (size_t)16 * Kdim, BsW + 512);
        __syncthreads();
        bf16x8 a[4], b[4];
        #pragma unroll
        for (int i = 0; i < 4; ++i)
            a[i] = *(const bf16x8*)(As + (wy * 64 + i * 16 + c) * 32 + g * 8);
        #pragma unroll
        for (int i = 0; i < 4; ++i)
            b[i] = *(const bf16x8*)(Bs + (wx * 64 + i * 16 + c) * 32 + g * 8);
        #pragma unroll
        for (int i = 0; i < 4; ++i)
            #pragma unroll
            for (int j = 0; j < 4; ++j)
                acc[i][j] = __builtin_amdgcn_mfma_f32_16x16x32_bf16(
                    a[i], b[j], acc[i][j], 0, 0, 0);
    }

    constexpr int VTHRESH = (EPI == 4) ? 2048 : 1024;
    constexpr int RPB     = (EPI == 4) ? 1024 : 2048;
    constexpr int KVL     = (EPI == 4) ? 1024 : 2048;

    #pragma unroll
    for (int i = 0; i < 4; ++i) {
        int row0 = m0 + wy * 64 + i * 16 + g * 4;
        #pragma unroll
        for (int j = 0; j < 4; ++j) {
            int col = n0 + wx * 64 + j * 16 + c;
            u16x4 o4;
            #pragma unroll
            for (int r = 0; r < 4; ++r) {
                float v = acc[i][j][r];
                size_t idx = (size_t)(row0 + r) * Ndim + col;
                if constexpr (EPI == 0 || EPI == 4 || EPI == 5) {
                    u16 bv = f2bf(v);
                    ((u16*)Cout)[idx] = bv;
                    o4[r] = bv;
                } else if constexpr (EPI == 1) {
                    v += bias[col];
                    v = 0.5f * v * (1.0f + erff(v * 0.70710678118654752f));
                    ((u16*)Cout)[idx] = f2bf(v);
                } else {
                    float* Cf = (float*)Cout;
                    Cf[idx] += v + bias[col];
                }
            }
            if constexpr (EPI == 4 || EPI == 5) {
                if (n0 + wx * 64 + j * 16 >= VTHRESH) {
                    int hh = (col - VTHRESH) >> 6;
                    int dd = col & 63;
                    int bi = row0 / RPB;
                    int kv = row0 % RPB;
                    *(u16x4*)&vt[(((size_t)bi * HEADS_ + hh) * 64 + dd) * KVL +
                                 kv] = o4;
                }
            }
        }
    }
}

// ---------------------------------------------------------------------------
// MFMA flash attention v2. Block = 4 waves, 64 q-rows (16/wave), one (b,h).
// KVBLK=64. Swapped QK^T (mfma(K,Q)) -> each lane owns q=lane&15's scores;
// in-register softmax (2 shfl_xor) ; P redistributed to PV A-fragment via
// 16 shfl + 8 select (no LDS round trip). K and V^T staged via
// global_load_lds with pre-swizzled global source (linear LDS = swizzled).
// V^T comes precomputed from the producing GEMM's epilogue.
// ---------------------------------------------------------------------------
template <int KLEN, int IS_SA>
__global__ __launch_bounds__(256) void attn_mfma2(
    const u16* __restrict__ Qsrc, const u16* __restrict__ Ksrc,
    const u16* __restrict__ Vtg, const int* __restrict__ mask,
    u16* __restrict__ O) {
    constexpr int QSTR = IS_SA ? 3 * INNER_ : INNER_;
    constexpr int KSTR = IS_SA ? 3 * INNER_ : 2 * INNER_;
    constexpr int KOFF = IS_SA ? INNER_ : 0;

    __shared__ __align__(16) u16 Ks[64 * 64];
    __shared__ __align__(16) u16 Vs[64 * 64];

    const int t = threadIdx.x;
    const int lane = t & 63, w = t >> 6;
    const int c = lane & 15, g = lane >> 4;
    const int h = blockIdx.y, bb = blockIdx.z;
    const int q0 = blockIdx.x * 64;
    const int kvbase = bb * KLEN;

    // Q fragments: B-operand rows q = q0 + w*16 + c
    const u16* qp =
        Qsrc + (size_t)(bb * N_ + q0 + w * 16 + c) * QSTR + h * 64 + g * 8;
    bf16x8 qf[2];
    qf[0] = *(const bf16x8*)qp;
    qf[1] = *(const bf16x8*)(qp + 32);

    // staging geometry: per gload instr, lane covers (row rbase+(lane>>3),
    // 16B col-block lane&7), source col-block pre-swizzled by row&7
    const int sl_r = lane >> 3;
    const int scol = ((lane & 7) ^ sl_r) * 8;  // swizzled source col (u16)
    const int r0 = w * 16, r1 = w * 16 + 8;
    const u16* Kg0 = Ksrc + (size_t)(kvbase + r0 + sl_r) * KSTR + KOFF +
                     h * 64 + scol;
    const u16* Kg1 = Ksrc + (size_t)(kvbase + r1 + sl_r) * KSTR + KOFF +
                     h * 64 + scol;
    const u16* Vg0 =
        Vtg + ((size_t)(bb * HEADS_ + h) * 64 + r0 + sl_r) * KLEN + scol;
    const u16* Vg1 =
        Vtg + ((size_t)(bb * HEADS_ + h) * 64 + r1 + sl_r) * KLEN + scol;

    f32x4 o[4] = {};
    float mr = -1e30f, lr = 0.f;
    const int srcA = c + 32 * (g & 1);
    const int srcB = srcA + 16;
    const bool hi = (g & 2) != 0;

    for (int kt = 0; kt < KLEN / 64; ++kt) {
        __syncthreads();
        GLOAD16(Kg0 + (size_t)kt * 64 * KSTR, Ks + r0 * 64);
        GLOAD16(Kg1 + (size_t)kt * 64 * KSTR, Ks + r1 * 64);
        GLOAD16(Vg0 + kt * 64, Vs + r0 * 64);
        GLOAD16(Vg1 + kt * 64, Vs + r1 * 64);
        float negm_reg = 0.f;
        if constexpr (IS_SA)
            negm_reg = 1e11f * (float)(1 - mask[bb * N_ + kt * 64 + lane]);
        __syncthreads();

        // S^T = K Q^T : sv[kvb] holds S[q = c][kv = kvb*16 + g*4 + r]
        f32x4 sv[4] = {};
        #pragma unroll
        for (int kvb = 0; kvb < 4; ++kvb) {
            #pragma unroll
            for (int f = 0; f < 2; ++f) {
                bf16x8 kf = *(const bf16x8*)(
                    Ks + (kvb * 16 + c) * 64 + (((g + 4 * f) ^ (c & 7)) * 8));
                sv[kvb] = __builtin_amdgcn_mfma_f32_16x16x32_bf16(
                    kf, qf[f], sv[kvb], 0, 0, 0);
            }
        }
        #pragma unroll
        for (int kvb = 0; kvb < 4; ++kvb)
            #pragma unroll
            for (int r = 0; r < 4; ++r) {
                float s = sv[kvb][r] * 0.125f;
                if constexpr (IS_SA)
                    s -= __shfl(negm_reg, kvb * 16 + g * 4 + r);
                sv[kvb][r] = s;
            }

        // row max over this tile (row q = c), combine g-groups
        float tm = sv[0][0];
        #pragma unroll
        for (int kvb = 0; kvb < 4; ++kvb)
            #pragma unroll
            for (int r = 0; r < 4; ++r) tm = fmaxf(tm, sv[kvb][r]);
        tm = fmaxf(tm, __shfl_xor(tm, 16));
        tm = fmaxf(tm, __shfl_xor(tm, 32));
        float mnew = fmaxf(mr, tm);
        float corr = __expf(mr - mnew);
        mr = mnew;

        float ps = 0.f;
        #pragma unroll
        for (int kvb = 0; kvb < 4; ++kvb)
            #pragma unroll
            for (int r = 0; r < 4; ++r) {
                float p = __expf(sv[kvb][r] - mr);
                sv[kvb][r] = p;
                ps += p;
            }
        ps += __shfl_xor(ps, 16);
        ps += __shfl_xor(ps, 32);
        lr = lr * corr + ps;

        float corrO[4];
        #pragma unroll
        for (int r = 0; r < 4; ++r) corrO[r] = __shfl(corr, g * 4 + r);
        #pragma unroll
        for (int db = 0; db < 4; ++db)
            #pragma unroll
            for (int r = 0; r < 4; ++r) o[db][r] *= corrO[r];

        // pack P to bf16 pairs: pk[kvb][j] = {kv kvb*16+g*4+2j, +2j+1}
        unsigned pk[4][2];
        #pragma unroll
        for (int kvb = 0; kvb < 4; ++kvb)
            #pragma unroll
            for (int j = 0; j < 2; ++j)
                pk[kvb][j] = ((unsigned)f2bf(sv[kvb][2 * j + 1]) << 16) |
                             (unsigned)f2bf(sv[kvb][2 * j]);

        // PV: A-frag lane (c,g) needs P[q=c][kv = pv*32 + g*8 + 0..7]
        #pragma unroll
        for (int pv = 0; pv < 2; ++pv) {
            int a0 = __shfl((int)pk[2 * pv][0], srcA);
            int b0 = __shfl((int)pk[2 * pv + 1][0], srcA);
            int a1 = __shfl((int)pk[2 * pv][1], srcA);
            int b1 = __shfl((int)pk[2 * pv + 1][1], srcA);
            int a2 = __shfl((int)pk[2 * pv][0], srcB);
            int b2 = __shfl((int)pk[2 * pv + 1][0], srcB);
            int a3 = __shfl((int)pk[2 * pv][1], srcB);
            int b3 = __shfl((int)pk[2 * pv + 1][1], srcB);
            i32x4 tw = {hi ? b0 : a0, hi ? b1 : a1, hi ? b2 : a2,
                        hi ? b3 : a3};
            bf16x8 pa = *(bf16x8*)&tw;
            #pragma unroll
            for (int db = 0; db < 4; ++db) {
                bf16x8 vf = *(const bf16x8*)(
                    Vs + (db * 16 + c) * 64 + (((g + 4 * pv) ^ (c & 7)) * 8));
                o[db] = __builtin_amdgcn_mfma_f32_16x16x32_bf16(pa, vf, o[db],
                                                                0, 0, 0);
            }
        }
    }

    float inv = 1.f / lr;
    float invO[4];
    #pragma unroll
    for (int r = 0; r < 4; ++r) invO[r] = __shfl(inv, g * 4 + r);
    #pragma unroll
    for (int db = 0; db < 4; ++db)
        #pragma unroll
        for (int r = 0; r < 4; ++r) {
            size_t idx =
                (size_t)(bb * N_ + q0 + w * 16 + g * 4 + r) * INNER_ +
                h * 64 + db * 16 + c;
            O[idx] = f2bf(o[db][r] * invO[r]);
        }
}

// ---------------------------------------------------------------------------
extern "C" void kernel_launch(void* const* d_in, const int* in_sizes, int n_in,
                              void* d_out, int out_size, void* d_ws,
                              size_t ws_size, hipStream_t stream) {
    const float* x     = (const float*)d_in[0];
    const float* ctx   = (const float*)d_in[1];
    const int*   mask  = (const int*)d_in[2];
    const float* ln_g  = (const float*)d_in[3];
    const float* ln_b  = (const float*)d_in[4];
    const float* Wqkv  = (const float*)d_in[5];
    const float* Wo_sa = (const float*)d_in[6];
    const float* bo_sa = (const float*)d_in[7];
    const float* Wkv   = (const float*)d_in[8];
    const float* Wq    = (const float*)d_in[9];
    const float* Wo_ca = (const float*)d_in[10];
    const float* bo_ca = (const float*)d_in[11];
    const float* W1    = (const float*)d_in[12];
    const float* b1    = (const float*)d_in[13];
    const float* W2    = (const float*)d_in[14];
    const float* b2    = (const float*)d_in[15];
    float* xout = (float*)d_out;

    char* ws = (char*)d_ws;
    u16* lnout = (u16*)ws;                        // 8MB (also attn out)
    u16* big   = (u16*)(ws + (8ull << 20));       // 32MB: qkv / kv / h1
    u16* qca   = (u16*)(ws + (40ull << 20));      // 8MB
    u16* ctxb  = (u16*)(ws + (48ull << 20));      // 16MB
    u16* wt    = (u16*)(ws + (64ull << 20));      // 8MB: transposed weight
    u16* vt_sa = (u16*)(ws + (72ull << 20));      // 8MB: V^T self-attn
    u16* vt_ca = (u16*)(ws + (80ull << 20));      // 16MB: V^T cross-attn
    u16* aout  = lnout;

    hipMemcpyAsync(xout, x, sizeof(float) * B_ * N_ * DIM_,
                   hipMemcpyDeviceToDevice, stream);
    cast_kernel<<<B_ * M_ * CTX_ / 1024, 256, 0, stream>>>(ctx, ctxb);

    const int ROWS = B_ * N_;    // 4096
    const int CROWS = B_ * M_;   // 8192
    dim3 blk(256);

    for (int i = 0; i < DEPTH_; ++i) {
        const float* g  = ln_g + (size_t)(i * 3) * DIM_;
        const float* bb = ln_b + (size_t)(i * 3) * DIM_;

        // ---- self-attention ----
        ln_kernel<<<ROWS, blk, 0, stream>>>(xout, g, bb, lnout);
        transpose_cast<<<dim3(3 * INNER_ / 32, DIM_ / 32), blk, 0, stream>>>(
            Wqkv + (size_t)i * DIM_ * 3 * INNER_, wt, DIM_, 3 * INNER_);
        gemm_mfma<4><<<dim3(3 * INNER_ / 128, ROWS / 128), blk, 0, stream>>>(
            lnout, wt, nullptr, big, vt_sa, ROWS, 3 * INNER_, DIM_);
        attn_mfma2<N_, 1><<<dim3(N_ / 64, HEADS_, B_), blk, 0, stream>>>(
            big, big, vt_sa, mask, aout);
        transpose_cast<<<dim3(DIM_ / 32, INNER_ / 32), blk, 0, stream>>>(
            Wo_sa + (size_t)i * INNER_ * DIM_, wt, INNER_, DIM_);
        gemm_mfma<2><<<dim3(DIM_ / 128, ROWS / 128), blk, 0, stream>>>(
            aout, wt, bo_sa + (size_t)i * DIM_, xout, nullptr, ROWS, DIM_,
            INNER_);

        // ---- cross-attention ----
        ln_kernel<<<ROWS, blk, 0, stream>>>(xout, g + DIM_, bb + DIM_, lnout);
        transpose_cast<<<dim3(INNER_ / 32, DIM_ / 32), blk, 0, stream>>>(
            Wq + (size_t)i * DIM_ * INNER_, wt, DIM_, INNER_);
        gemm_mfma<0><<<dim3(INNER_ / 128, ROWS / 128), blk, 0, stream>>>(
            lnout, wt, nullptr, qca, nullptr, ROWS, INNER_, DIM_);
        transpose_cast<<<dim3(2 * INNER_ / 32, CTX_ / 32), blk, 0, stream>>>(
            Wkv + (size_t)i * CTX_ * 2 * INNER_, wt, CTX_, 2 * INNER_);
        gemm_mfma<5><<<dim3(2 * INNER_ / 128, CROWS / 128), blk, 0, stream>>>(
            ctxb, wt, nullptr, big, vt_ca, CROWS, 2 * INNER_, CTX_);
        attn_mfma2<M_, 0><<<dim3(N_ / 64, HEADS_, B_), blk, 0, stream>>>(
            qca, big, vt_ca, mask, aout);
        transpose_cast<<<dim3(DIM_ / 32, INNER_ / 32), blk, 0, stream>>>(
            Wo_ca + (size_t)i * INNER_ * DIM_, wt, INNER_, DIM_);
        gemm_mfma<2><<<dim3(DIM_ / 128, ROWS / 128), blk, 0, stream>>>(
            aout, wt, bo_ca + (size_t)i * DIM_, xout, nullptr, ROWS, DIM_,
            INNER_);

        // ---- feed-forward ----
        ln_kernel<<<ROWS, blk, 0, stream>>>(xout, g + 2 * DIM_, bb + 2 * DIM_,
                                            lnout);
        transpose_cast<<<dim3(MLP_ / 32, DIM_ / 32), blk, 0, stream>>>(
            W1 + (size_t)i * DIM_ * MLP_, wt, DIM_, MLP_);
        gemm_mfma<1><<<dim3(MLP_ / 128, ROWS / 128), blk, 0, stream>>>(
            lnout, wt, b1 + (size_t)i * MLP_, big, nullptr, ROWS, MLP_, DIM_);
        transpose_cast<<<dim3(DIM_ / 32, MLP_ / 32), blk, 0, stream>>>(
            W2 + (size_t)i * MLP_ * DIM_, wt, MLP_, DIM_);
        gemm_mfma<2><<<dim3(DIM_ / 128, ROWS / 128), blk, 0, stream>>>(
            big, wt, b2 + (size_t)i * DIM_, xout, nullptr, ROWS, DIM_, MLP_);
    }
}